// Round 14
// baseline (363.715 us; speedup 1.0000x reference)
//
#include <hip/hip_runtime.h>
#include <stdint.h>

#define BATCH   8
#define LEN0    8192
#define EMB     768
#define POOLED  512    // LEN0 >> 4
#define NJC     16     // j-chunks in level-0 rank
#define PL      (BATCH * LEN0)

struct __align__(16) Rec { uint32_t iA, iB; float w0, w1; };

// ---------------------------------------------------------------------------
// ws layout (bytes):
//   rank16 : BATCH*LEN0 u16        @ 0x080000  (128 KiB)
//   ior16  : BATCH*LEN0 u16        @ 0x0A0000  (128 KiB)
//   rec0   : 4096*8 Rec            @ 0x0C0000  (512 KiB)
//   rec1   : 2048*8 Rec            @ 0x140000  (256 KiB)
//   rec2   : 1024*8 Rec            @ 0x180000  (128 KiB)
//   rec3   :  512*8 Rec            @ 0x1A0000  ( 64 KiB)
//   rankp  : NJC planes BATCH*LEN0 u16 @ 0x1C0000 (2 MiB)
//   scF    : BATCH*POOLED f32      @ 0x3C0000  ( 16 KiB)
// NO atomics, NO fences, NO memset: kernel boundaries are the only sync.
// (Rounds 9/10/13 measured agent-scope coherence at ~25-100 µs per use;
//  a graph-captured launch edge is ~8 µs. Redundant compute wins.)
// ---------------------------------------------------------------------------

// Bit-faithful replication of numpy's SIMD float32 exp — DO NOT TOUCH.
// (Round 5 proved this exact sequence makes ranks match the numpy golden.)
__device__ __forceinline__ float npy_expf(float x) {
    const float q = rintf(__fmul_rn(x, 1.44269504088896341f)); // LOG2EF
    float r = __fmaf_rn(q, -0.693359375f, x);       // fnmadd(q, C1, x)
    r = __fmaf_rn(q, 2.12194440e-4f, r);            // fnmadd(q, C2, x)
    const float r2 = __fmul_rn(r, r);
    float p = 1.9875691500E-4f;
    p = __fmaf_rn(p, r, 1.3981999507E-3f);
    p = __fmaf_rn(p, r, 8.3334519073E-3f);
    p = __fmaf_rn(p, r, 4.1665795894E-2f);
    p = __fmaf_rn(p, r, 1.6666665459E-1f);
    p = __fmaf_rn(p, r, 5.0000001201E-1f);
    p = __fmaf_rn(p, r2, r);
    p = __fadd_rn(p, 1.0f);
    const int qi = (int)q;
    const float sc = __uint_as_float((uint32_t)((qi + 127) << 23));
    return __fmul_rn(p, sc);
}

// FROZEN pair softmax (round 5).
__device__ __forceinline__ void pair_softmax(float s0, float s1,
                                             float& w0, float& w1, float& ns) {
    const float p0 = (float)exp2((double)s0);   // np.power(2,s) == glibc powf
    const float p1 = (float)exp2((double)s1);
    const float mx = fmaxf(p0, p1);
    const float d0 = __fsub_rn(p0, mx);
    const float d1 = __fsub_rn(p1, mx);
    const float e0 = npy_expf(d0);
    const float e1 = npy_expf(d1);
    const float den = __fadd_rn(e0, e1);
    w0 = __fdiv_rn(e0, den);
    w1 = __fdiv_rn(e1, den);
    ns = __fadd_rn(__fmul_rn(s0, w0), __fmul_rn(s1, w1));
}

// u64 sort key (verified round 12): ascending == stable argsort(-score);
// high bits recover the score BIT-EXACTLY.
__device__ __forceinline__ unsigned long long make_key(float s, int idx) {
    const uint32_t u = __float_as_uint(s);
    const uint32_t asc = u ^ ((uint32_t)((int32_t)u >> 31) | 0x80000000u);
    const uint32_t d = ~asc;
    return ((unsigned long long)d << 16) | (uint32_t)idx;
}
__device__ __forceinline__ float key_score(unsigned long long k) {
    const uint32_t asc = ~(uint32_t)(k >> 16);
    const uint32_t u = asc ^ ((asc & 0x80000000u) ? 0x80000000u : 0xFFFFFFFFu);
    return __uint_as_float(u);
}

// Level-0 chunked rank-by-count (verbatim round 11, verified).
__global__ __launch_bounds__(256) void k_rank(const float* __restrict__ sc,
                                              uint16_t* __restrict__ rankp,
                                              int L, int C) {
    __shared__ float keys[512];
    const int b     = blockIdx.z;
    const int jc    = blockIdx.y;
    const int base  = b * LEN0;
    const int ibase = blockIdx.x * 1024;
    const int jb    = jc * C;
    const int tid   = threadIdx.x;

    for (int j = tid; j < C; j += 256)
        keys[j] = sc[base + jb + j];
    __syncthreads();

    const int i0 = ibase + tid * 4;
    const float4 mev = *(const float4*)&sc[base + i0];
    const float me[4] = {mev.x, mev.y, mev.z, mev.w};
    uint32_t cnt[4] = {0, 0, 0, 0};
    if (jb + C <= ibase) {             // all j < i: ties count
        for (int j = 0; j < C; j += 4) {
            const float4 kv = *(const float4*)&keys[j];
            #pragma unroll
            for (int m = 0; m < 4; m++)
                cnt[m] += (kv.x >= me[m]) + (kv.y >= me[m]) +
                          (kv.z >= me[m]) + (kv.w >= me[m]);
        }
    } else if (jb >= ibase + 1024) {   // all j > i: ties don't count
        for (int j = 0; j < C; j += 4) {
            const float4 kv = *(const float4*)&keys[j];
            #pragma unroll
            for (int m = 0; m < 4; m++)
                cnt[m] += (kv.x > me[m]) + (kv.y > me[m]) +
                          (kv.z > me[m]) + (kv.w > me[m]);
        }
    } else {                           // diagonal: full stable predicate
        for (int j = 0; j < C; j += 4) {
            const float4 kv = *(const float4*)&keys[j];
            const int jj = jb + j;
            #pragma unroll
            for (int m = 0; m < 4; m++) {
                const int i = i0 + m;
                cnt[m] += ((kv.x > me[m]) || (kv.x == me[m] && (jj    ) < i))
                        + ((kv.y > me[m]) || (kv.y == me[m] && (jj + 1) < i))
                        + ((kv.z > me[m]) || (kv.z == me[m] && (jj + 2) < i))
                        + ((kv.w > me[m]) || (kv.w == me[m] && (jj + 3) < i));
            }
        }
    }
    *(ushort4*)&rankp[(size_t)jc * PL + base + i0] =
        make_ushort4((uint16_t)cnt[0], (uint16_t)cnt[1],
                     (uint16_t)cnt[2], (uint16_t)cnt[3]);
}

// Sum NJC partial planes -> rank16; scatter ior16 (verbatim round 11).
__global__ __launch_bounds__(256) void k_sumscatter(const uint16_t* __restrict__ rankp,
                                                    uint16_t* __restrict__ rank16,
                                                    uint16_t* __restrict__ ior16) {
    const int b    = blockIdx.y;
    const int base = b * LEN0;
    const int i    = blockIdx.x * 256 + threadIdx.x;

    uint32_t r = 0;
    #pragma unroll
    for (int pl = 0; pl < NJC; pl++)
        r += rankp[(size_t)pl * PL + base + i];
    rank16[base + i] = (uint16_t)r;
    ior16[base + r] = (uint16_t)i;
}

// In-LDS level (adapted from round-12 verified tail_level; 256 threads,
// redundant across 32 blocks/batch, rec writes sliced by i-range).
template<int N>
__device__ __forceinline__ void tail_level(float* ns, unsigned long long* key,
                                           uint16_t* rnk, uint32_t* part,
                                           Rec* __restrict__ rec,
                                           int sub, int tid) {
    constexpr int HALF  = N / 2;
    constexpr int R     = N / 256;     // 16,8,4
    constexpr int SLICE = N / 32;      // i-range per block

    for (int e = tid; e < N; e += 256)
        key[e] = make_key(ns[e], e);
    __syncthreads();

    for (int k = 2; k <= N; k <<= 1) {            // bitonic sort, ascending
        for (int j = k >> 1; j > 0; j >>= 1) {
            for (int e = tid; e < N; e += 256) {
                const int pe = e ^ j;
                if (pe > e) {
                    const unsigned long long a = key[e];
                    const unsigned long long c = key[pe];
                    const bool up = ((e & k) == 0);
                    if ((a > c) == up) { key[e] = c; key[pe] = a; }
                }
            }
            __syncthreads();
        }
    }

    for (int e = tid; e < N; e += 256)
        rnk[(uint32_t)(key[e] & 0xFFFFu)] = (uint16_t)e;
    __syncthreads();

    // flags + scan in INDEX order (SORT_BACK dst)
    const int i0 = tid * R;
    uint16_t rr[R];
    uint32_t loc = 0;
    #pragma unroll
    for (int m = 0; m < R; m++) {
        rr[m] = rnk[i0 + m];
        loc += (rr[m] < HALF) ? 1u : 0u;
    }
    part[tid] = loc;
    __syncthreads();
    for (int off = 1; off < 256; off <<= 1) {
        uint32_t v = part[tid];
        uint32_t add = (tid >= off) ? part[tid - off] : 0u;
        __syncthreads();
        part[tid] = v + add;
        __syncthreads();
    }
    uint32_t dst = (tid > 0) ? part[tid - 1] : 0u;

    #pragma unroll
    for (int m = 0; m < R; m++) {
        const uint32_t r = rr[m];
        if (r >= HALF) continue;
        const int i = i0 + m;
        const unsigned long long kp = key[N - 1 - r];
        const uint32_t p = (uint32_t)(kp & 0xFFFFu);
        const float s0 = key_score(key[r]);       // == ns[i], bit-exact
        const float s1 = key_score(kp);
        float w0, w1, nsv;
        pair_softmax(s0, s1, w0, w1, nsv);
        ns[dst] = nsv;                            // all blocks: identical values
        if (i / SLICE == sub) {                   // slice-owned Rec write
            Rec rc; rc.iA = (uint32_t)i; rc.iB = p; rc.w0 = w0; rc.w1 = w1;
            rec[dst] = rc;
        }
        dst++;
    }
    __syncthreads();
}

// Levels 0(pair)..3 for one batch, redundantly per block, slice-owned writes.
// grid (32, BATCH), 256 thr, ~57 KiB LDS -> 1 block/CU, 256 blocks total.
__global__ __launch_bounds__(256)
void k_tail2(const float* __restrict__ scores,
             const uint16_t* __restrict__ rank16, const uint16_t* __restrict__ ior16,
             Rec* __restrict__ rec0, Rec* __restrict__ rec1,
             Rec* __restrict__ rec2, Rec* __restrict__ rec3,
             float* __restrict__ scF) {
    __shared__ unsigned long long key[4096];   // 32 KiB
    __shared__ float    ns[4096];              // 16 KiB
    __shared__ uint16_t rnk[4096];             //  8 KiB
    __shared__ uint32_t part[256];             //  1 KiB
    const int sub  = blockIdx.x;               // 0..31
    const int b    = blockIdx.y;
    const int base = b * LEN0;
    const int tid  = threadIdx.x;

    // ---- level 0 pair (L=8192): ranks/ior from global, dst scan in-block ----
    {
        const int i0 = tid * 32;
        uint16_t rr[32];
        #pragma unroll
        for (int m = 0; m < 32; m += 4)
            *(ushort4*)&rr[m] = *(const ushort4*)&rank16[base + i0 + m];
        uint32_t loc = 0;
        #pragma unroll
        for (int m = 0; m < 32; m++) loc += (rr[m] < 4096) ? 1u : 0u;
        part[tid] = loc;
        __syncthreads();
        for (int off = 1; off < 256; off <<= 1) {
            uint32_t v = part[tid];
            uint32_t add = (tid >= off) ? part[tid - off] : 0u;
            __syncthreads();
            part[tid] = v + add;
            __syncthreads();
        }
        uint32_t dst = (tid > 0) ? part[tid - 1] : 0u;
        #pragma unroll
        for (int m = 0; m < 32; m++) {
            const uint32_t r = rr[m];
            if (r >= 4096) continue;
            const int i = i0 + m;
            const uint32_t p = ior16[base + 8191 - r];
            const float s0 = scores[base + i];
            const float s1 = scores[base + p];
            float w0, w1, nsv;
            pair_softmax(s0, s1, w0, w1, nsv);
            ns[dst] = nsv;                        // redundant, identical
            if ((i >> 8) == sub) {                // slice = 256 i's per block
                Rec rc; rc.iA = (uint32_t)i; rc.iB = p; rc.w0 = w0; rc.w1 = w1;
                rec0[(size_t)b * 4096 + dst] = rc;
            }
            dst++;
        }
        __syncthreads();
    }

    tail_level<4096>(ns, key, rnk, part, rec1 + (size_t)b * 2048, sub, tid);
    tail_level<2048>(ns, key, rnk, part, rec2 + (size_t)b * 1024, sub, tid);
    tail_level<1024>(ns, key, rnk, part, rec3 + (size_t)b * 512,  sub, tid);

    if (sub == 0)
        for (int s = tid; s < POOLED; s += 256)
            scF[b * POOLED + s] = ns[s];
}

// Final gather: expand 4-level pair tree -> 16 leaves (verified rounds 9-13).
__global__ __launch_bounds__(192)
void k_merge(const float* __restrict__ emb,
             const Rec* __restrict__ rec0, const Rec* __restrict__ rec1,
             const Rec* __restrict__ rec2, const Rec* __restrict__ rec3,
             const float* __restrict__ sc_fin, float* __restrict__ out) {
    __shared__ uint32_t sl[2][16];
    __shared__ float    sw[2][16];
    const int s = blockIdx.x;
    const int b = blockIdx.y;
    const int d = threadIdx.x;

    if (d == 0) {
        const Rec r = rec3[b * 512 + s];
        sl[0][0] = r.iA; sl[0][1] = r.iB;
        sw[0][0] = r.w0; sw[0][1] = r.w1;
    }
    __syncthreads();
    if (d < 2) {
        const Rec r = rec2[b * 1024 + sl[0][d]];
        sl[1][2*d] = r.iA; sl[1][2*d+1] = r.iB;
        sw[1][2*d]   = __fmul_rn(sw[0][d], r.w0);
        sw[1][2*d+1] = __fmul_rn(sw[0][d], r.w1);
    }
    __syncthreads();
    if (d < 4) {
        const Rec r = rec1[b * 2048 + sl[1][d]];
        sl[0][2*d] = r.iA; sl[0][2*d+1] = r.iB;
        sw[0][2*d]   = __fmul_rn(sw[1][d], r.w0);
        sw[0][2*d+1] = __fmul_rn(sw[1][d], r.w1);
    }
    __syncthreads();
    if (d < 8) {
        const Rec r = rec0[b * 4096 + sl[0][d]];   // iA/iB = original rows
        sl[1][2*d] = r.iA; sl[1][2*d+1] = r.iB;
        sw[1][2*d]   = __fmul_rn(sw[0][d], r.w0);
        sw[1][2*d+1] = __fmul_rn(sw[0][d], r.w1);
    }
    __syncthreads();

    const float* ebase = emb + (size_t)b * LEN0 * EMB;
    float4 acc = make_float4(0.f, 0.f, 0.f, 0.f);
    #pragma unroll
    for (int k = 0; k < 16; k++) {
        const float4 v = *(const float4*)(ebase + (size_t)sl[1][k] * EMB + d * 4);
        const float wk = sw[1][k];
        acc.x += wk * v.x; acc.y += wk * v.y; acc.z += wk * v.z; acc.w += wk * v.w;
    }
    *(float4*)(out + ((size_t)b * POOLED + s) * EMB + d * 4) = acc;
    if (d == 0)
        out[(size_t)BATCH * POOLED * EMB + b * POOLED + s] = sc_fin[b * POOLED + s];
}

extern "C" void kernel_launch(void* const* d_in, const int* in_sizes, int n_in,
                              void* d_out, int out_size, void* d_ws, size_t ws_size,
                              hipStream_t stream) {
    const float* embs   = (const float*)d_in[0];
    const float* scores = (const float*)d_in[1];
    float* out = (float*)d_out;
    char* ws = (char*)d_ws;

    uint16_t* rank16 = (uint16_t*)(ws + 0x080000);
    uint16_t* ior16  = (uint16_t*)(ws + 0x0A0000);
    Rec*      rec0   = (Rec*)(ws + 0x0C0000);
    Rec*      rec1   = (Rec*)(ws + 0x140000);
    Rec*      rec2   = (Rec*)(ws + 0x180000);
    Rec*      rec3   = (Rec*)(ws + 0x1A0000);
    uint16_t* rankp  = (uint16_t*)(ws + 0x1C0000);
    float*    scF    = (float*)(ws + 0x3C0000);

    k_rank<<<dim3(LEN0 / 1024, NJC, BATCH), 256, 0, stream>>>(scores, rankp,
                                                              LEN0, LEN0 / NJC);
    k_sumscatter<<<dim3(LEN0 / 256, BATCH), 256, 0, stream>>>(rankp, rank16, ior16);
    k_tail2<<<dim3(32, BATCH), 256, 0, stream>>>(scores, rank16, ior16,
                                                 rec0, rec1, rec2, rec3, scF);
    k_merge<<<dim3(POOLED, BATCH), 192, 0, stream>>>(embs, rec0, rec1, rec2, rec3,
                                                     scF, out);
}

// Round 15
// 216.582 us; speedup vs baseline: 1.6793x; 1.6793x over previous
//
#include <hip/hip_runtime.h>
#include <stdint.h>

#define BATCH   8
#define LEN0    8192
#define EMB     768
#define POOLED  512    // LEN0 >> 4

struct __align__(16) Rec { uint32_t iA, iB; float w0, w1; };

// ---------------------------------------------------------------------------
// ws layout (bytes):
//   scA    : BATCH*LEN0 f32   @ 0x000000  (256 KiB)
//   scB    : BATCH*LEN0 f32   @ 0x040000
//   rank16 : BATCH*LEN0 u16   @ 0x080000  (128 KiB)
//   ior16  : BATCH*LEN0 u16   @ 0x0A0000  (128 KiB)
//   rec0   : 4096*8 Rec       @ 0x0C0000  (512 KiB)
//   rec1   : 2048*8 Rec       @ 0x140000  (256 KiB)
//   rec2   : 1024*8 Rec       @ 0x180000  (128 KiB)
//   rec3   :  512*8 Rec       @ 0x1A0000  ( 64 KiB)
//   csum   : BATCH*32 u32     @ 0x3C0000  (  1 KiB)
// NO atomics, NO fences, NO memset — kernel boundaries are the only sync.
// (Measured: launch edge ~8 µs; agent-scope fence/atomic patterns 25-100 µs;
//  single/few-block phases 100+ µs.  Wide + boundaries wins — rounds 9-14.)
// ---------------------------------------------------------------------------

// Bit-faithful replication of numpy's SIMD float32 exp — DO NOT TOUCH.
// (Round 5 proved this exact sequence makes ranks match the numpy golden.)
__device__ __forceinline__ float npy_expf(float x) {
    const float q = rintf(__fmul_rn(x, 1.44269504088896341f)); // LOG2EF
    float r = __fmaf_rn(q, -0.693359375f, x);       // fnmadd(q, C1, x)
    r = __fmaf_rn(q, 2.12194440e-4f, r);            // fnmadd(q, C2, x)
    const float r2 = __fmul_rn(r, r);
    float p = 1.9875691500E-4f;
    p = __fmaf_rn(p, r, 1.3981999507E-3f);
    p = __fmaf_rn(p, r, 8.3334519073E-3f);
    p = __fmaf_rn(p, r, 4.1665795894E-2f);
    p = __fmaf_rn(p, r, 1.6666665459E-1f);
    p = __fmaf_rn(p, r, 5.0000001201E-1f);
    p = __fmaf_rn(p, r2, r);
    p = __fadd_rn(p, 1.0f);
    const int qi = (int)q;
    const float sc = __uint_as_float((uint32_t)((qi + 127) << 23));
    return __fmul_rn(p, sc);
}

// Full-rank in one kernel: each block owns 256 i's and loops over ALL j in
// 512-float LDS-staged chunks (stable ascending-index ties).  Writes rank16,
// scatters ior16, and block-reduces the per-256-chunk top-flag count -> csum.
// grid (L/256, BATCH), 256 thr.
__global__ __launch_bounds__(256) void k_rankall(const float* __restrict__ sc,
                                                 uint16_t* __restrict__ rank16,
                                                 uint16_t* __restrict__ ior16,
                                                 uint32_t* __restrict__ csum,
                                                 int L) {
    __shared__ float keys[512];
    __shared__ uint32_t part[256];
    const int b     = blockIdx.y;
    const int base  = b * LEN0;
    const int ibase = blockIdx.x * 256;
    const int tid   = threadIdx.x;
    const int i     = ibase + tid;
    const float me  = sc[base + i];

    uint32_t cnt = 0;
    for (int jb = 0; jb < L; jb += 512) {
        __syncthreads();
        keys[tid]       = sc[base + jb + tid];
        keys[tid + 256] = sc[base + jb + tid + 256];
        __syncthreads();
        if (jb + 512 <= ibase) {           // all j < i: ties count
            #pragma unroll 4
            for (int j = 0; j < 512; j += 4) {
                const float4 kv = *(const float4*)&keys[j];
                cnt += (kv.x >= me) + (kv.y >= me) + (kv.z >= me) + (kv.w >= me);
            }
        } else if (jb >= ibase + 256) {    // all j > i: ties don't count
            #pragma unroll 4
            for (int j = 0; j < 512; j += 4) {
                const float4 kv = *(const float4*)&keys[j];
                cnt += (kv.x > me) + (kv.y > me) + (kv.z > me) + (kv.w > me);
            }
        } else {                           // diagonal chunk: full predicate
            for (int j = 0; j < 512; j += 4) {
                const float4 kv = *(const float4*)&keys[j];
                const int jj = jb + j;
                cnt += ((kv.x > me) || (kv.x == me && (jj    ) < i))
                     + ((kv.y > me) || (kv.y == me && (jj + 1) < i))
                     + ((kv.z > me) || (kv.z == me && (jj + 2) < i))
                     + ((kv.w > me) || (kv.w == me && (jj + 3) < i));
            }
        }
    }
    rank16[base + i] = (uint16_t)cnt;
    ior16[base + cnt] = (uint16_t)i;       // ranks unique -> inverse perm

    const uint32_t half = (uint32_t)(L / 2);
    part[tid] = (cnt < half) ? 1u : 0u;
    __syncthreads();
    for (int off = 128; off > 0; off >>= 1) {
        if (tid < off) part[tid] += part[tid + off];
        __syncthreads();
    }
    if (tid == 0) csum[b * 32 + blockIdx.x] = part[0];
}

// Wide pair phase (verbatim round 11, verified): chunk dst-base from csum,
// in-block flag scan, softmax (NUMERICS FROZEN, round 5), Rec write.
// grid (L/256, BATCH), 256 thr.
__global__ __launch_bounds__(256) void k_pairx(const float* __restrict__ sc_cur,
                                               float* __restrict__ sc_nxt,
                                               const uint16_t* __restrict__ rank16,
                                               const uint16_t* __restrict__ ior16,
                                               const uint32_t* __restrict__ csum,
                                               Rec* __restrict__ rec,
                                               int L) {
    __shared__ uint32_t cs[32];
    __shared__ uint32_t part[256];
    const int b    = blockIdx.y;
    const int base = b * LEN0;
    const int c    = blockIdx.x;
    const int tid  = threadIdx.x;
    const int i    = c * 256 + tid;
    const uint32_t half = (uint32_t)(L / 2);

    if (tid < c) cs[tid] = csum[b * 32 + tid];
    const uint32_t r = rank16[base + i];
    const uint32_t flag = (r < half) ? 1u : 0u;
    part[tid] = flag;
    __syncthreads();

    uint32_t dstBase = 0;
    for (int t = 0; t < c; t++) dstBase += cs[t];   // LDS broadcast reads

    for (int off = 1; off < 256; off <<= 1) {       // Hillis-Steele inclusive
        uint32_t v = part[tid];
        uint32_t add = (tid >= off) ? part[tid - off] : 0u;
        __syncthreads();
        part[tid] = v + add;
        __syncthreads();
    }
    if (!flag) return;
    const uint32_t dst = dstBase + part[tid] - 1u;  // exclusive within chunk

    const uint32_t p = ior16[base + (uint32_t)(L - 1) - r];
    const float s0 = sc_cur[base + i];
    const float s1 = sc_cur[base + p];
    // np.power(2.0, s): glibc powf (correctly rounded); exp2 in double
    // rounded to f32 reproduces it.
    const float p0 = (float)exp2((double)s0);
    const float p1 = (float)exp2((double)s1);
    const float mx = fmaxf(p0, p1);
    const float d0 = __fsub_rn(p0, mx);
    const float d1 = __fsub_rn(p1, mx);
    const float e0 = npy_expf(d0);
    const float e1 = npy_expf(d1);
    const float den = __fadd_rn(e0, e1);
    const float w0 = __fdiv_rn(e0, den);
    const float w1 = __fdiv_rn(e1, den);
    sc_nxt[base + dst] = __fadd_rn(__fmul_rn(s0, w0), __fmul_rn(s1, w1));

    Rec rc; rc.iA = (uint32_t)i; rc.iB = p; rc.w0 = w0; rc.w1 = w1;
    rec[(size_t)b * half + dst] = rc;
}

// Final gather: expand 4-level pair tree -> 16 leaves (verified rounds 9-14).
__global__ __launch_bounds__(192)
void k_merge(const float* __restrict__ emb,
             const Rec* __restrict__ rec0, const Rec* __restrict__ rec1,
             const Rec* __restrict__ rec2, const Rec* __restrict__ rec3,
             const float* __restrict__ sc_fin, float* __restrict__ out) {
    __shared__ uint32_t sl[2][16];
    __shared__ float    sw[2][16];
    const int s = blockIdx.x;
    const int b = blockIdx.y;
    const int d = threadIdx.x;

    if (d == 0) {
        const Rec r = rec3[b * 512 + s];
        sl[0][0] = r.iA; sl[0][1] = r.iB;
        sw[0][0] = r.w0; sw[0][1] = r.w1;
    }
    __syncthreads();
    if (d < 2) {
        const Rec r = rec2[b * 1024 + sl[0][d]];
        sl[1][2*d] = r.iA; sl[1][2*d+1] = r.iB;
        sw[1][2*d]   = __fmul_rn(sw[0][d], r.w0);
        sw[1][2*d+1] = __fmul_rn(sw[0][d], r.w1);
    }
    __syncthreads();
    if (d < 4) {
        const Rec r = rec1[b * 2048 + sl[1][d]];
        sl[0][2*d] = r.iA; sl[0][2*d+1] = r.iB;
        sw[0][2*d]   = __fmul_rn(sw[1][d], r.w0);
        sw[0][2*d+1] = __fmul_rn(sw[1][d], r.w1);
    }
    __syncthreads();
    if (d < 8) {
        const Rec r = rec0[b * 4096 + sl[0][d]];   // iA/iB = original rows
        sl[1][2*d] = r.iA; sl[1][2*d+1] = r.iB;
        sw[1][2*d]   = __fmul_rn(sw[0][d], r.w0);
        sw[1][2*d+1] = __fmul_rn(sw[0][d], r.w1);
    }
    __syncthreads();

    const float* ebase = emb + (size_t)b * LEN0 * EMB;
    float4 acc = make_float4(0.f, 0.f, 0.f, 0.f);
    #pragma unroll
    for (int k = 0; k < 16; k++) {
        const float4 v = *(const float4*)(ebase + (size_t)sl[1][k] * EMB + d * 4);
        const float wk = sw[1][k];
        acc.x += wk * v.x; acc.y += wk * v.y; acc.z += wk * v.z; acc.w += wk * v.w;
    }
    *(float4*)(out + ((size_t)b * POOLED + s) * EMB + d * 4) = acc;
    if (d == 0)
        out[(size_t)BATCH * POOLED * EMB + b * POOLED + s] = sc_fin[b * LEN0 + s];
}

extern "C" void kernel_launch(void* const* d_in, const int* in_sizes, int n_in,
                              void* d_out, int out_size, void* d_ws, size_t ws_size,
                              hipStream_t stream) {
    const float* embs   = (const float*)d_in[0];
    const float* scores = (const float*)d_in[1];
    float* out = (float*)d_out;
    char* ws = (char*)d_ws;

    float*    scA    = (float*)(ws + 0x000000);
    float*    scB    = (float*)(ws + 0x040000);
    uint16_t* rank16 = (uint16_t*)(ws + 0x080000);
    uint16_t* ior16  = (uint16_t*)(ws + 0x0A0000);
    Rec*      rec0   = (Rec*)(ws + 0x0C0000);
    Rec*      rec1   = (Rec*)(ws + 0x140000);
    Rec*      rec2   = (Rec*)(ws + 0x180000);
    Rec*      rec3   = (Rec*)(ws + 0x1A0000);
    uint32_t* csum   = (uint32_t*)(ws + 0x3C0000);

    const float* sc_in[4]  = {scores, scA, scB, scA};
    float*       sc_out[4] = {scA, scB, scA, scB};
    Rec*         recs[4]   = {rec0, rec1, rec2, rec3};

    int L = LEN0;
    for (int l = 0; l < 4; l++) {
        k_rankall<<<dim3(L / 256, BATCH), 256, 0, stream>>>(sc_in[l], rank16,
                                                            ior16, csum, L);
        k_pairx<<<dim3(L / 256, BATCH), 256, 0, stream>>>(sc_in[l], sc_out[l],
                                                          rank16, ior16, csum,
                                                          recs[l], L);
        L >>= 1;
    }

    k_merge<<<dim3(POOLED, BATCH), 192, 0, stream>>>(embs, rec0, rec1, rec2, rec3,
                                                     scB, out);
}

// Round 16
// 146.070 us; speedup vs baseline: 2.4900x; 1.4827x over previous
//
#include <hip/hip_runtime.h>
#include <stdint.h>

#define BATCH   8
#define LEN0    8192
#define EMB     768
#define POOLED  512    // LEN0 >> 4

struct __align__(16) Rec { uint32_t iA, iB; float w0, w1; };

// ---------------------------------------------------------------------------
// ws layout (bytes):
//   scA    : BATCH*LEN0 f32   @ 0x000000  (256 KiB)
//   scB    : BATCH*LEN0 f32   @ 0x040000
//   rank16 : BATCH*LEN0 u16   @ 0x080000  (128 KiB)
//   ior16  : BATCH*LEN0 u16   @ 0x0A0000  (128 KiB)
//   rec0   : 4096*8 Rec       @ 0x0C0000  (512 KiB)
//   rec1   : 2048*8 Rec       @ 0x140000  (256 KiB)
//   rec2   : 1024*8 Rec       @ 0x180000  (128 KiB)
//   rec3   :  512*8 Rec       @ 0x1A0000  ( 64 KiB)
//   csum   : BATCH*32 u32     @ 0x3C0000  (  1 KiB)
// NO atomics, NO fences, NO memset — kernel boundaries are the only sync.
// (Measured rounds 9-15: launch edge ~8 µs; agent-scope fences 25-100 µs;
//  narrow/low-occupancy kernels 100+ µs.  Wide + boundaries wins.)
// ---------------------------------------------------------------------------

// Bit-faithful replication of numpy's SIMD float32 exp — DO NOT TOUCH.
// (Round 5 proved this exact sequence makes ranks match the numpy golden.)
__device__ __forceinline__ float npy_expf(float x) {
    const float q = rintf(__fmul_rn(x, 1.44269504088896341f)); // LOG2EF
    float r = __fmaf_rn(q, -0.693359375f, x);       // fnmadd(q, C1, x)
    r = __fmaf_rn(q, 2.12194440e-4f, r);            // fnmadd(q, C2, x)
    const float r2 = __fmul_rn(r, r);
    float p = 1.9875691500E-4f;
    p = __fmaf_rn(p, r, 1.3981999507E-3f);
    p = __fmaf_rn(p, r, 8.3334519073E-3f);
    p = __fmaf_rn(p, r, 4.1665795894E-2f);
    p = __fmaf_rn(p, r, 1.6666665459E-1f);
    p = __fmaf_rn(p, r, 5.0000001201E-1f);
    p = __fmaf_rn(p, r2, r);
    p = __fadd_rn(p, 1.0f);
    const int qi = (int)q;
    const float sc = __uint_as_float((uint32_t)((qi + 127) << 23));
    return __fmul_rn(p, sc);
}

// Full rank in ONE kernel with round-11's parallelism shape inside the block:
// grid (32, BATCH), 1024 thr (16 waves/CU, every CU busy at every level).
// Whole score array staged in LDS (<=32 KiB); threads = G j-groups x IC/4
// i-quads; per-thread = (JR/4) b128 broadcast reads x 4 i's (MI=4).
// Stable ascending-index ties.  Writes rank16, ior16, per-block csum.
template<int L>
__global__ __launch_bounds__(1024) void k_rankfull(const float* __restrict__ sc,
                                                   uint16_t* __restrict__ rank16,
                                                   uint16_t* __restrict__ ior16,
                                                   uint32_t* __restrict__ csum) {
    constexpr int IC = L / 32;         // i's per block: 256,128,64,32
    constexpr int IQ = IC / 4;         // i-quads: 64,32,16,8
    constexpr int G  = 1024 / IQ;      // j-groups: 16,32,64,128
    constexpr int JR = L / G;          // j-range per group: 512,128,32,8
    __shared__ float    keys[L];       // whole batch score array (<=32 KiB)
    __shared__ uint16_t partial[4096]; // [G][IC] = 4096 entries (8 KiB)
    __shared__ uint32_t wsum[16];
    const int b     = blockIdx.y;
    const int base  = b * LEN0;
    const int ibase = blockIdx.x * IC;
    const int tid   = threadIdx.x;

    for (int e = tid * 4; e < L; e += 4096)
        *(float4*)&keys[e] = *(const float4*)&sc[base + e];
    __syncthreads();

    const int iq  = tid % IQ;
    const int g   = tid / IQ;
    const int i0  = ibase + iq * 4;
    const int jlo = g * JR;
    const float4 mev = *(const float4*)&keys[i0];
    const float me[4] = {mev.x, mev.y, mev.z, mev.w};

    uint32_t cnt[4] = {0, 0, 0, 0};
    if (jlo + JR <= i0) {              // all j < i (every i in quad): ties count
        for (int j = jlo; j < jlo + JR; j += 4) {
            const float4 kv = *(const float4*)&keys[j];
            #pragma unroll
            for (int m = 0; m < 4; m++)
                cnt[m] += (kv.x >= me[m]) + (kv.y >= me[m]) +
                          (kv.z >= me[m]) + (kv.w >= me[m]);
        }
    } else if (jlo >= i0 + 4) {        // all j > i: ties don't count
        for (int j = jlo; j < jlo + JR; j += 4) {
            const float4 kv = *(const float4*)&keys[j];
            #pragma unroll
            for (int m = 0; m < 4; m++)
                cnt[m] += (kv.x > me[m]) + (kv.y > me[m]) +
                          (kv.z > me[m]) + (kv.w > me[m]);
        }
    } else {                           // diagonal window: full stable predicate
        for (int j = jlo; j < jlo + JR; j += 4) {
            const float4 kv = *(const float4*)&keys[j];
            #pragma unroll
            for (int m = 0; m < 4; m++) {
                const int i = i0 + m;
                cnt[m] += ((kv.x > me[m]) || (kv.x == me[m] && (j    ) < i))
                        + ((kv.y > me[m]) || (kv.y == me[m] && (j + 1) < i))
                        + ((kv.z > me[m]) || (kv.z == me[m] && (j + 2) < i))
                        + ((kv.w > me[m]) || (kv.w == me[m] && (j + 3) < i));
            }
        }
    }
    *(ushort4*)&partial[g * IC + iq * 4] =
        make_ushort4((uint16_t)cnt[0], (uint16_t)cnt[1],
                     (uint16_t)cnt[2], (uint16_t)cnt[3]);
    __syncthreads();

    // IC threads: sum G partials -> full rank; scatter; flag for csum
    uint32_t flag = 0;
    if (tid < IC) {
        uint32_t r = 0;
        #pragma unroll 4
        for (int gg = 0; gg < G; gg++)
            r += partial[gg * IC + tid];
        const int i = ibase + tid;
        rank16[base + i] = (uint16_t)r;
        ior16[base + r] = (uint16_t)i;     // ranks unique -> inverse perm
        flag = (r < (uint32_t)(L / 2)) ? 1u : 0u;
    }
    // wave-reduce flags (lanes with tid>=IC contribute 0), then combine
    #pragma unroll
    for (int off = 32; off > 0; off >>= 1)
        flag += __shfl_down(flag, off, 64);
    if ((tid & 63) == 0) wsum[tid >> 6] = flag;
    __syncthreads();
    if (tid == 0) {
        uint32_t s = 0;
        constexpr int NW = (IC + 63) / 64;   // waves holding flags
        #pragma unroll
        for (int w = 0; w < NW; w++) s += wsum[w];
        csum[b * 32 + blockIdx.x] = s;
    }
}

// Wide pair phase (round 11, verified; dstBase generalized to IC-granular
// csum): chunk dst-base from csum, in-block flag scan, softmax (NUMERICS
// FROZEN, round 5), Rec write.  grid (L/256, BATCH), 256 thr.
__global__ __launch_bounds__(256) void k_pairx(const float* __restrict__ sc_cur,
                                               float* __restrict__ sc_nxt,
                                               const uint16_t* __restrict__ rank16,
                                               const uint16_t* __restrict__ ior16,
                                               const uint32_t* __restrict__ csum,
                                               Rec* __restrict__ rec,
                                               int L, int NCHPB) {
    __shared__ uint32_t cs[32];
    __shared__ uint32_t part[256];
    const int b    = blockIdx.y;
    const int base = b * LEN0;
    const int c    = blockIdx.x;
    const int tid  = threadIdx.x;
    const int i    = c * 256 + tid;
    const uint32_t half = (uint32_t)(L / 2);

    if (tid < 32) cs[tid] = csum[b * 32 + tid];
    const uint32_t r = rank16[base + i];
    const uint32_t flag = (r < half) ? 1u : 0u;
    part[tid] = flag;
    __syncthreads();

    uint32_t dstBase = 0;
    const int nch = c * NCHPB;                      // csum chunks before block
    for (int t = 0; t < nch; t++) dstBase += cs[t]; // LDS broadcast reads

    for (int off = 1; off < 256; off <<= 1) {       // Hillis-Steele inclusive
        uint32_t v = part[tid];
        uint32_t add = (tid >= off) ? part[tid - off] : 0u;
        __syncthreads();
        part[tid] = v + add;
        __syncthreads();
    }
    if (!flag) return;
    const uint32_t dst = dstBase + part[tid] - 1u;  // exclusive within chunk

    const uint32_t p = ior16[base + (uint32_t)(L - 1) - r];
    const float s0 = sc_cur[base + i];
    const float s1 = sc_cur[base + p];
    // np.power(2.0, s): glibc powf (correctly rounded); exp2 in double
    // rounded to f32 reproduces it.
    const float p0 = (float)exp2((double)s0);
    const float p1 = (float)exp2((double)s1);
    const float mx = fmaxf(p0, p1);
    const float d0 = __fsub_rn(p0, mx);
    const float d1 = __fsub_rn(p1, mx);
    const float e0 = npy_expf(d0);
    const float e1 = npy_expf(d1);
    const float den = __fadd_rn(e0, e1);
    const float w0 = __fdiv_rn(e0, den);
    const float w1 = __fdiv_rn(e1, den);
    sc_nxt[base + dst] = __fadd_rn(__fmul_rn(s0, w0), __fmul_rn(s1, w1));

    Rec rc; rc.iA = (uint32_t)i; rc.iB = p; rc.w0 = w0; rc.w1 = w1;
    rec[(size_t)b * half + dst] = rc;
}

// Final gather: expand 4-level pair tree -> 16 leaves (verified rounds 9-15).
__global__ __launch_bounds__(192)
void k_merge(const float* __restrict__ emb,
             const Rec* __restrict__ rec0, const Rec* __restrict__ rec1,
             const Rec* __restrict__ rec2, const Rec* __restrict__ rec3,
             const float* __restrict__ sc_fin, float* __restrict__ out) {
    __shared__ uint32_t sl[2][16];
    __shared__ float    sw[2][16];
    const int s = blockIdx.x;
    const int b = blockIdx.y;
    const int d = threadIdx.x;

    if (d == 0) {
        const Rec r = rec3[b * 512 + s];
        sl[0][0] = r.iA; sl[0][1] = r.iB;
        sw[0][0] = r.w0; sw[0][1] = r.w1;
    }
    __syncthreads();
    if (d < 2) {
        const Rec r = rec2[b * 1024 + sl[0][d]];
        sl[1][2*d] = r.iA; sl[1][2*d+1] = r.iB;
        sw[1][2*d]   = __fmul_rn(sw[0][d], r.w0);
        sw[1][2*d+1] = __fmul_rn(sw[0][d], r.w1);
    }
    __syncthreads();
    if (d < 4) {
        const Rec r = rec1[b * 2048 + sl[1][d]];
        sl[0][2*d] = r.iA; sl[0][2*d+1] = r.iB;
        sw[0][2*d]   = __fmul_rn(sw[1][d], r.w0);
        sw[0][2*d+1] = __fmul_rn(sw[1][d], r.w1);
    }
    __syncthreads();
    if (d < 8) {
        const Rec r = rec0[b * 4096 + sl[0][d]];   // iA/iB = original rows
        sl[1][2*d] = r.iA; sl[1][2*d+1] = r.iB;
        sw[1][2*d]   = __fmul_rn(sw[0][d], r.w0);
        sw[1][2*d+1] = __fmul_rn(sw[0][d], r.w1);
    }
    __syncthreads();

    const float* ebase = emb + (size_t)b * LEN0 * EMB;
    float4 acc = make_float4(0.f, 0.f, 0.f, 0.f);
    #pragma unroll
    for (int k = 0; k < 16; k++) {
        const float4 v = *(const float4*)(ebase + (size_t)sl[1][k] * EMB + d * 4);
        const float wk = sw[1][k];
        acc.x += wk * v.x; acc.y += wk * v.y; acc.z += wk * v.z; acc.w += wk * v.w;
    }
    *(float4*)(out + ((size_t)b * POOLED + s) * EMB + d * 4) = acc;
    if (d == 0)
        out[(size_t)BATCH * POOLED * EMB + b * POOLED + s] = sc_fin[b * LEN0 + s];
}

extern "C" void kernel_launch(void* const* d_in, const int* in_sizes, int n_in,
                              void* d_out, int out_size, void* d_ws, size_t ws_size,
                              hipStream_t stream) {
    const float* embs   = (const float*)d_in[0];
    const float* scores = (const float*)d_in[1];
    float* out = (float*)d_out;
    char* ws = (char*)d_ws;

    float*    scA    = (float*)(ws + 0x000000);
    float*    scB    = (float*)(ws + 0x040000);
    uint16_t* rank16 = (uint16_t*)(ws + 0x080000);
    uint16_t* ior16  = (uint16_t*)(ws + 0x0A0000);
    Rec*      rec0   = (Rec*)(ws + 0x0C0000);
    Rec*      rec1   = (Rec*)(ws + 0x140000);
    Rec*      rec2   = (Rec*)(ws + 0x180000);
    Rec*      rec3   = (Rec*)(ws + 0x1A0000);
    uint32_t* csum   = (uint32_t*)(ws + 0x3C0000);

    const dim3 rg(32, BATCH);

    k_rankfull<8192><<<rg, 1024, 0, stream>>>(scores, rank16, ior16, csum);
    k_pairx<<<dim3(32, BATCH), 256, 0, stream>>>(scores, scA, rank16, ior16,
                                                 csum, rec0, 8192, 1);
    k_rankfull<4096><<<rg, 1024, 0, stream>>>(scA, rank16, ior16, csum);
    k_pairx<<<dim3(16, BATCH), 256, 0, stream>>>(scA, scB, rank16, ior16,
                                                 csum, rec1, 4096, 2);
    k_rankfull<2048><<<rg, 1024, 0, stream>>>(scB, rank16, ior16, csum);
    k_pairx<<<dim3(8, BATCH), 256, 0, stream>>>(scB, scA, rank16, ior16,
                                                csum, rec2, 2048, 4);
    k_rankfull<1024><<<rg, 1024, 0, stream>>>(scA, rank16, ior16, csum);
    k_pairx<<<dim3(4, BATCH), 256, 0, stream>>>(scA, scB, rank16, ior16,
                                                csum, rec3, 1024, 8);

    k_merge<<<dim3(POOLED, BATCH), 192, 0, stream>>>(embs, rec0, rec1, rec2, rec3,
                                                     scB, out);
}